// Round 3
// baseline (167.094 us; speedup 1.0000x reference)
//
#include <hip/hip_runtime.h>
#include <hip/hip_bf16.h>
#include <math.h>

constexpr int N = 16384, D = 256, C = 10000;
constexpr float S = 30.0f, MARGIN = 0.4f;
constexpr int BM = 128, BN = 128, BK = 64;
constexpr int CP = ((C + BN - 1) / BN) * BN; // 10112
constexpr int NX = N / BM;                   // 128 row tiles
constexpr int NY = CP / BN;                  // 79 col tiles
constexpr int NWG = NX * NY;                 // 10112
constexpr float S_LOG2E = 43.2808512266689f; // S * log2(e)

using bf16 = __hip_bfloat16;
typedef __attribute__((ext_vector_type(8))) short short8;
typedef __attribute__((ext_vector_type(4))) short short4v;
typedef __attribute__((ext_vector_type(4))) float f32x4;

// ---------------- prep: normalize x -> bf16 (pre-scaled by S*log2e), tgt f32 ----------------
// one WAVE per row, no barriers; float4 loads, 8B bf16 stores
__global__ __launch_bounds__(256) void prep_x(const float* __restrict__ x,
                                              const int* __restrict__ labels,
                                              const float* __restrict__ W,
                                              bf16* __restrict__ xn,
                                              float* __restrict__ tgt) {
    const int w = threadIdx.x >> 6, lane = threadIdx.x & 63;
    const int row = blockIdx.x * 4 + w;

    f32x4 v = *(const f32x4*)(x + row * D + lane * 4);
    float sq = v.x * v.x + v.y * v.y + v.z * v.z + v.w * v.w;
    #pragma unroll
    for (int off = 1; off < 64; off <<= 1) sq += __shfl_xor(sq, off);
    float rinv = rsqrtf(sq);

    f32x4 xv = { v.x * rinv, v.y * rinv, v.z * rinv, v.w * rinv };
    short4v sv;
    sv.x = (short)__bfloat16_as_ushort(__float2bfloat16(xv.x * S_LOG2E));
    sv.y = (short)__bfloat16_as_ushort(__float2bfloat16(xv.y * S_LOG2E));
    sv.z = (short)__bfloat16_as_ushort(__float2bfloat16(xv.z * S_LOG2E));
    sv.w = (short)__bfloat16_as_ushort(__float2bfloat16(xv.w * S_LOG2E));
    *(short4v*)(xn + row * D + lane * 4) = sv;

    const int lab = labels[row];
    f32x4 wr = *(const f32x4*)(W + (size_t)lab * D + lane * 4);
    float t = xv.x * wr.x + xv.y * wr.y + xv.z * wr.z + xv.w * wr.w;
    #pragma unroll
    for (int off = 1; off < 64; off <<= 1) t += __shfl_xor(t, off);
    if (lane == 0) tgt[row] = t;
}

// ---------------- prep: W f32 -> bf16, zero-pad rows [C, CP), 4 elems/thread ----------------
__global__ __launch_bounds__(256) void prep_w(const float* __restrict__ W,
                                              bf16* __restrict__ Wb) {
    int i = (blockIdx.x * 256 + threadIdx.x) * 4;   // over CP*D
    int r = i >> 8;                                  // D == 256
    short4v sv;
    if (r < C) {
        f32x4 v = *(const f32x4*)(W + i);
        sv.x = (short)__bfloat16_as_ushort(__float2bfloat16(v.x));
        sv.y = (short)__bfloat16_as_ushort(__float2bfloat16(v.y));
        sv.z = (short)__bfloat16_as_ushort(__float2bfloat16(v.z));
        sv.w = (short)__bfloat16_as_ushort(__float2bfloat16(v.w));
    } else {
        sv = short4v{0, 0, 0, 0};
    }
    *(short4v*)(Wb + i) = sv;
}

// ---------------- main GEMM + exp2 + per-tile row partials ----------------
// XCD-chunked mapping: xcd = bid&7 owns x-tiles [16*xcd, 16*xcd+16) (1 MB of A,
// L2-resident) and sweeps y panels. LDS tiles [128][64] bf16, XOR-swizzled
// (linear global_load_lds dest + pre-swizzled source + swizzled ds_read).
__global__ __launch_bounds__(256) void gemm_exp(const bf16* __restrict__ A,   // xn [N][D]
                                                const bf16* __restrict__ B,   // Wb [CP][D]
                                                float* __restrict__ partial) { // [NY][N]
    __shared__ __align__(16) bf16 As[BM * BK];   // 16 KB
    __shared__ __align__(16) bf16 Bs[BN * BK];   // 16 KB

    // ---- XCD-aware decode (bijective: NWG = 8 * 1264, 1264 = 16 * 79) ----
    const int bid = blockIdx.x;
    const int xcd = bid & 7;
    const int idx = bid >> 3;          // 0..1263
    const int xl  = idx & 15;          // x within XCD chunk (fast)
    const int y   = idx >> 4;          // 0..78 (slow)
    const int tile_r = (xcd * 16 + xl) * BM;
    const int tile_c = y * BN;

    const int t = threadIdx.x;
    const int lane = t & 63, w = t >> 6;
    const int wm = w >> 1, wn = w & 1;      // 2x2 wave grid, each wave 64x64

    f32x4 acc[4][4] = {};

    // staging geometry: 1 KB chunk = 8 rows x 128 B; lane l covers row l>>3, slot l&7
    const int srow  = lane >> 3;             // row within chunk (== row&7)
    const int sslot = (lane & 7) ^ srow;     // pre-swizzled source slot

    for (int k0 = 0; k0 < D; k0 += BK) {
        #pragma unroll
        for (int q = 0; q < 4; ++q) {
            int c = w * 4 + q;                // chunk 0..15 (wave-uniform)
            int rloc = c * 8 + srow;
            const bf16* ga = A + (size_t)(tile_r + rloc) * D + k0 + sslot * 8;
            const bf16* gb = B + (size_t)(tile_c + rloc) * D + k0 + sslot * 8;
            __builtin_amdgcn_global_load_lds(
                (const __attribute__((address_space(1))) void*)ga,
                (__attribute__((address_space(3))) void*)(As + c * 512),
                16, 0, 0);
            __builtin_amdgcn_global_load_lds(
                (const __attribute__((address_space(1))) void*)gb,
                (__attribute__((address_space(3))) void*)(Bs + c * 512),
                16, 0, 0);
        }
        __syncthreads();   // drains vmcnt(0) -> staged data visible

        #pragma unroll
        for (int kk = 0; kk < 2; ++kk) {
            short8 af[4], bfr[4];
            #pragma unroll
            for (int m = 0; m < 4; ++m) {
                int row = wm * 64 + m * 16 + (lane & 15);
                int slot = (kk * 4 + (lane >> 4)) ^ (lane & 7);  // row&7 == lane&7
                af[m] = *(const short8*)(As + row * 64 + slot * 8);
            }
            #pragma unroll
            for (int n = 0; n < 4; ++n) {
                int row = wn * 64 + n * 16 + (lane & 15);
                int slot = (kk * 4 + (lane >> 4)) ^ (lane & 7);
                bfr[n] = *(const short8*)(Bs + row * 64 + slot * 8);
            }
            #pragma unroll
            for (int m = 0; m < 4; ++m)
                #pragma unroll
                for (int n = 0; n < 4; ++n)
                    acc[m][n] = __builtin_amdgcn_mfma_f32_16x16x32_bf16(af[m], bfr[n], acc[m][n], 0, 0, 0);
        }
        __syncthreads();  // all reads done before next overwrite / LDS reuse
    }

    // ---- epilogue: exp2(acc), mask padded cols, per-row sums -> LDS -> one store/row ----
    float* eps = (float*)As;   // reuse LDS: 128 rows x 2 halves = 1 KB

    #pragma unroll
    for (int m = 0; m < 4; ++m) {
        float rs[4] = {0.f, 0.f, 0.f, 0.f};
        #pragma unroll
        for (int n = 0; n < 4; ++n) {
            int gcol = tile_c + wn * 64 + n * 16 + (lane & 15);
            bool ok = (gcol < C);
            #pragma unroll
            for (int r = 0; r < 4; ++r) {
                float e = ok ? __builtin_amdgcn_exp2f(acc[m][n][r]) : 0.0f;
                rs[r] += e;
            }
        }
        #pragma unroll
        for (int r = 0; r < 4; ++r) {
            float v = rs[r];
            v += __shfl_xor(v, 1);
            v += __shfl_xor(v, 2);
            v += __shfl_xor(v, 4);
            v += __shfl_xor(v, 8);
            if ((lane & 15) == 0) {
                int rl = wm * 64 + m * 16 + (lane >> 4) * 4 + r;
                eps[rl * 2 + wn] = v;
            }
        }
    }
    __syncthreads();
    if (t < 128) {
        float v = eps[t * 2 + 0] + eps[t * 2 + 1];
        partial[(size_t)y * N + tile_r + t] = v;   // coalesced 128-float store
    }
}

// ---------------- loss: reduce partials + per-row loss + block partial sums ----------------
__global__ __launch_bounds__(256) void loss_part(const float* __restrict__ tgt,
                                                 const float* __restrict__ partial,
                                                 float* __restrict__ partial2) {
    int i = blockIdx.x * 256 + threadIdx.x;   // row
    float sum = 0.0f;
    #pragma unroll 1
    for (int y = 0; y < NY; ++y) sum += partial[(size_t)y * N + i];  // coalesced per y

    float tg = tgt[i];
    float num = S * (tg - MARGIN);
    float den = __expf(num) + sum - __expf(S * tg);
    float L = num - logf(den);

    float v = L;
    #pragma unroll
    for (int off = 1; off < 64; off <<= 1) v += __shfl_xor(v, off);
    __shared__ float s4[4];
    int lane = threadIdx.x & 63, w = threadIdx.x >> 6;
    if (lane == 0) s4[w] = v;
    __syncthreads();
    if (threadIdx.x == 0) partial2[blockIdx.x] = s4[0] + s4[1] + s4[2] + s4[3];
}

__global__ void loss_final(const float* __restrict__ partial2, float* __restrict__ out) {
    float v = partial2[threadIdx.x];   // 64 threads, 64 partials
    #pragma unroll
    for (int off = 1; off < 64; off <<= 1) v += __shfl_xor(v, off);
    if (threadIdx.x == 0) out[0] = -v / (float)N;
}

// ---------------- launch ----------------
extern "C" void kernel_launch(void* const* d_in, const int* in_sizes, int n_in,
                              void* d_out, int out_size, void* d_ws, size_t ws_size,
                              hipStream_t stream) {
    const float* x = (const float*)d_in[0];
    const int* labels = (const int*)d_in[1];
    const float* W = (const float*)d_in[2];

    char* ws = (char*)d_ws;
    bf16* xn       = (bf16*)(ws);                    // N*D*2       =  8,388,608
    bf16* Wb       = (bf16*)(ws + 8388608);          // CP*D*2      =  5,177,344
    float* tgt     = (float*)(ws + 13565952);        // N*4         =     65,536
    float* partial = (float*)(ws + 13631488);        // NY*N*4      =  5,177,344
    float* partial2= (float*)(ws + 18808832);        // 64*4
    float* out = (float*)d_out;

    prep_x<<<N / 4, 256, 0, stream>>>(x, labels, W, xn, tgt);
    prep_w<<<(CP * D) / 1024, 256, 0, stream>>>(W, Wb);

    gemm_exp<<<NWG, 256, 0, stream>>>(xn, Wb, partial);

    loss_part<<<N / 256, 256, 0, stream>>>(tgt, partial, partial2);
    loss_final<<<1, 64, 0, stream>>>(partial2, out);
}